// Round 1
// baseline (1909.536 us; speedup 1.0000x reference)
//
#include <hip/hip_runtime.h>
#include <math.h>

// Problem shape (fixed by the bench's setup_inputs)
#define NS 16384
#define ND 2048
#define NC 1000

#define MS 64          // samples per block
#define CS 256         // classes per chunk (4 chunks cover 1024 >= 1000, tail masked)
#define KT 32          // k-tile in floats (8 float4 slots per row)
#define NCHUNK 4

// 256 threads = 4 waves. Per-thread 8x8 register tile:
//   tx = tid&31 -> 8 classes (cL = tx*8), ty = tid>>5 -> 8 samples (m0 = ty*8).
// msh k-slot swizzled by (c>>3) so the 8-row lane stride doesn't collapse all
// 32 lanes into one 4-bank column (would be 32-way conflict; swizzle -> 4-way
// inherent minimum).
__global__ __launch_bounds__(256, 1)
void nnc_fp32_kernel(const float* __restrict__ x,
                     const float* __restrict__ means,
                     float* __restrict__ out)
{
    __shared__ float xs[MS * KT];      // 8 KB, unswizzled (ty-broadcast reads)
    __shared__ float msh[CS * KT];     // 32 KB, swizzled
    __shared__ float rbest[MS * 33];
    __shared__ int   ridx[MS * 33];
    __shared__ int   widx[MS];

    const int tid = threadIdx.x;
    const int tx  = tid & 31;
    const int ty  = tid >> 5;
    const int s0  = blockIdx.x * MS;
    const int m0  = ty * 8;
    const int cL  = tx * 8;

    float best[8];
    int   bidx[8];
#pragma unroll
    for (int i = 0; i < 8; ++i) { best[i] = -INFINITY; bidx[i] = 0; }

    const int kslot = tid & 7;   // float4 slot within a KT row
    const int rrow  = tid >> 3;  // 0..31

    for (int chunk = 0; chunk < NCHUNK; ++chunk) {
        const int c0 = chunk * CS;
        float acc[8][8];
#pragma unroll
        for (int i = 0; i < 8; ++i)
#pragma unroll
            for (int j = 0; j < 8; ++j) acc[i][j] = 0.0f;

        for (int k0 = 0; k0 < ND; k0 += KT) {
            // ---- stage x tile: 64 rows x 32 k (coalesced, 128B per 8 lanes) ----
#pragma unroll
            for (int r = 0; r < 2; ++r) {
                const int m = rrow + r * 32;
                const float4 v =
                    *(const float4*)(x + (size_t)(s0 + m) * ND + k0 + kslot * 4);
                *(float4*)(xs + m * KT + kslot * 4) = v;
            }
            // ---- stage means tile: 256 rows x 32 k, swizzled k-slot ----
#pragma unroll
            for (int r = 0; r < 8; ++r) {
                const int c  = rrow + r * 32;
                const int cg = c0 + c;
                float4 v = make_float4(0.f, 0.f, 0.f, 0.f);
                if (cg < NC)
                    v = *(const float4*)(means + (size_t)cg * ND + k0 + kslot * 4);
                const int pslot = (kslot + (c >> 3)) & 7;
                *(float4*)(msh + c * KT + pslot * 4) = v;
            }
            __syncthreads();
            // ---- 8x8 outer-product accumulation ----
#pragma unroll
            for (int k4 = 0; k4 < KT / 4; ++k4) {
                float4 a[8], b[8];
                const int boff = ((k4 + tx) & 7) * 4;  // rows cL..cL+7 share c>>3==tx
#pragma unroll
                for (int i = 0; i < 8; ++i)
                    a[i] = *(const float4*)(xs + (m0 + i) * KT + k4 * 4);
#pragma unroll
                for (int j = 0; j < 8; ++j)
                    b[j] = *(const float4*)(msh + (cL + j) * KT + boff);
#pragma unroll
                for (int i = 0; i < 8; ++i)
#pragma unroll
                    for (int j = 0; j < 8; ++j) {
                        acc[i][j] = fmaf(a[i].x, b[j].x, acc[i][j]);
                        acc[i][j] = fmaf(a[i].y, b[j].y, acc[i][j]);
                        acc[i][j] = fmaf(a[i].z, b[j].z, acc[i][j]);
                        acc[i][j] = fmaf(a[i].w, b[j].w, acc[i][j]);
                    }
            }
            __syncthreads();
        }
        // fold this chunk into the running per-thread best (first-index-wins ties)
#pragma unroll
        for (int i = 0; i < 8; ++i)
#pragma unroll
            for (int j = 0; j < 8; ++j) {
                const int c = c0 + cL + j;
                const float v = acc[i][j];
                if (c < NC && (v > best[i] || (v == best[i] && c < bidx[i]))) {
                    best[i] = v;
                    bidx[i] = c;
                }
            }
    }

    // ---- cross-thread (tx) argmax reduction per sample ----
#pragma unroll
    for (int i = 0; i < 8; ++i) {
        rbest[(m0 + i) * 33 + tx] = best[i];
        ridx[(m0 + i) * 33 + tx]  = bidx[i];
    }
    __syncthreads();
    if (tid < MS) {
        float bv = rbest[tid * 33];
        int   bc = ridx[tid * 33];
        for (int t = 1; t < 32; ++t) {
            const float v = rbest[tid * 33 + t];
            const int   c = ridx[tid * 33 + t];
            if (v > bv || (v == bv && c < bc)) { bv = v; bc = c; }
        }
        widx[tid] = bc;
    }
    __syncthreads();

    // ---- write one-hot rows: block owns its 64 full rows (no memset needed;
    //      d_out is re-poisoned 0xAA before every launch) ----
    if (tid < 250) {
        const int cbase = tid * 4;
        for (int m = 0; m < MS; ++m) {
            const int w = widx[m];
            float4 v;
            v.x = (cbase == w) ? 1.f : 0.f;
            v.y = (cbase + 1 == w) ? 1.f : 0.f;
            v.z = (cbase + 2 == w) ? 1.f : 0.f;
            v.w = (cbase + 3 == w) ? 1.f : 0.f;
            *(float4*)(out + (size_t)(s0 + m) * NC + cbase) = v;
        }
    }
}

extern "C" void kernel_launch(void* const* d_in, const int* in_sizes, int n_in,
                              void* d_out, int out_size, void* d_ws, size_t ws_size,
                              hipStream_t stream) {
    const float* x     = (const float*)d_in[0];
    const float* means = (const float*)d_in[1];
    float* out         = (float*)d_out;
    // d_in[2] (n_classes scalar) intentionally unused: shape is fixed at 1000.
    dim3 grid(NS / MS);
    dim3 block(256);
    nnc_fp32_kernel<<<grid, block, 0, stream>>>(x, means, out);
}

// Round 2
// 453.678 us; speedup vs baseline: 4.2090x; 4.2090x over previous
//
#include <hip/hip_runtime.h>
#include <math.h>

// Problem shape (fixed by the bench's setup_inputs)
#define NS 16384
#define ND 2048
#define NC 1000
#define NCPAD 1024

typedef _Float16 f16x8 __attribute__((ext_vector_type(8)));
typedef _Float16 f16x4 __attribute__((ext_vector_type(4)));
typedef float f32x4 __attribute__((ext_vector_type(4)));

// ---------------------------------------------------------------------------
// Workspace layout (bytes):
//   xhi  : NS*ND*2          =  67108864
//   xlo  : NS*ND*2          =  67108864
//   mhi  : NCPAD*ND*2       =   4194304
//   mlo  : NCPAD*ND*2       =   4194304
//   score: NS*NCPAD*4       =  67108864
//   total                   = 209715200
// ---------------------------------------------------------------------------
#define WS_NEEDED 209715200ull

__device__ __forceinline__ void gl_lds16(const _Float16* g, _Float16* l) {
    __builtin_amdgcn_global_load_lds(
        (const __attribute__((address_space(1))) unsigned int*)g,
        (__attribute__((address_space(3))) unsigned int*)l, 16, 0, 0);
}

// ---- kernel 1a: split x (fp32 -> f16 hi + f16 lo), 1 float4 per thread ----
__global__ __launch_bounds__(256)
void split_x_kernel(const float* __restrict__ src,
                    _Float16* __restrict__ hi, _Float16* __restrict__ lo)
{
    const int i = blockIdx.x * 256 + threadIdx.x;   // float4 slot, < NS*ND/4
    const float4 v = ((const float4*)src)[i];
    f16x4 h, l;
    h[0] = (_Float16)v.x; l[0] = (_Float16)(v.x - (float)h[0]);
    h[1] = (_Float16)v.y; l[1] = (_Float16)(v.y - (float)h[1]);
    h[2] = (_Float16)v.z; l[2] = (_Float16)(v.z - (float)h[2]);
    h[3] = (_Float16)v.w; l[3] = (_Float16)(v.w - (float)h[3]);
    ((f16x4*)hi)[i] = h;
    ((f16x4*)lo)[i] = l;
}

// ---- kernel 1b: split means with zero padding to NCPAD rows ----
__global__ __launch_bounds__(256)
void split_m_kernel(const float* __restrict__ src,
                    _Float16* __restrict__ hi, _Float16* __restrict__ lo)
{
    const int i = blockIdx.x * 256 + threadIdx.x;   // float4 slot, < NCPAD*ND/4
    const int row = (i * 4) >> 11;                  // /ND
    float4 v = make_float4(0.f, 0.f, 0.f, 0.f);
    if (row < NC) v = ((const float4*)src)[i];
    f16x4 h, l;
    h[0] = (_Float16)v.x; l[0] = (_Float16)(v.x - (float)h[0]);
    h[1] = (_Float16)v.y; l[1] = (_Float16)(v.y - (float)h[1]);
    h[2] = (_Float16)v.z; l[2] = (_Float16)(v.z - (float)h[2]);
    h[3] = (_Float16)v.w; l[3] = (_Float16)(v.w - (float)h[3]);
    ((f16x4*)hi)[i] = h;
    ((f16x4*)lo)[i] = l;
}

// ---- kernel 2: 128x128-tile split-f16 MFMA GEMM -> scores fp32 -------------
// grid (NS/128, NCPAD/128); 256 threads = 4 waves in 2x2 wave grid;
// wave tile 64x64 = 4x4 MFMAs of 16x16x32. BK=32, single LDS buffer (m97).
// 3 accumulate passes per k-step: hi*hi + hi*lo + lo*hi.
__global__ __launch_bounds__(256, 2)
void gemm_split_kernel(const _Float16* __restrict__ xhi,
                       const _Float16* __restrict__ xlo,
                       const _Float16* __restrict__ mhi,
                       const _Float16* __restrict__ mlo,
                       float* __restrict__ scores)
{
    __shared__ _Float16 sAh[128 * 32];
    __shared__ _Float16 sAl[128 * 32];
    __shared__ _Float16 sBh[128 * 32];
    __shared__ _Float16 sBl[128 * 32];

    const int tid  = threadIdx.x;
    const int lane = tid & 63;
    const int w    = tid >> 6;
    const int wm   = w & 1, wn = w >> 1;
    const int quad = lane >> 4, l16 = lane & 15;
    const size_t gm0 = (size_t)blockIdx.x * 128;
    const size_t gn0 = (size_t)blockIdx.y * 128;

    f32x4 acc[4][4] = {};

    for (int kt = 0; kt < ND / 32; ++kt) {
        const int k0 = kt * 32;
        // stage 4 tiles of 128x32 f16 (8 KB each) via direct-to-LDS, 16B/lane
#pragma unroll
        for (int r = 0; r < 2; ++r) {
            const int slot = r * 256 + tid;          // 0..511
            const int row  = slot >> 2;
            const int kc   = slot & 3;
            const size_t ga = ((gm0 + row) << 11) + k0 + kc * 8;
            const size_t gb = ((gn0 + row) << 11) + k0 + kc * 8;
            const int lbase = (r * 256 + w * 64) * 8;  // wave-uniform LDS base
            gl_lds16(xhi + ga, &sAh[lbase]);
            gl_lds16(xlo + ga, &sAl[lbase]);
            gl_lds16(mhi + gb, &sBh[lbase]);
            gl_lds16(mlo + gb, &sBl[lbase]);
        }
        __syncthreads();

        f16x8 ah[4], al[4], bh[4], bl[4];
#pragma unroll
        for (int i = 0; i < 4; ++i) {
            const int ar = wm * 64 + i * 16 + l16;
            const int br = wn * 64 + i * 16 + l16;
            const int ko = quad * 8;
            ah[i] = *(const f16x8*)&sAh[ar * 32 + ko];
            al[i] = *(const f16x8*)&sAl[ar * 32 + ko];
            bh[i] = *(const f16x8*)&sBh[br * 32 + ko];
            bl[i] = *(const f16x8*)&sBl[br * 32 + ko];
        }
#pragma unroll
        for (int i = 0; i < 4; ++i)
#pragma unroll
            for (int j = 0; j < 4; ++j) {
                acc[i][j] = __builtin_amdgcn_mfma_f32_16x16x32_f16(ah[i], bh[j], acc[i][j], 0, 0, 0);
                acc[i][j] = __builtin_amdgcn_mfma_f32_16x16x32_f16(ah[i], bl[j], acc[i][j], 0, 0, 0);
                acc[i][j] = __builtin_amdgcn_mfma_f32_16x16x32_f16(al[i], bh[j], acc[i][j], 0, 0, 0);
            }
        __syncthreads();
    }

    // epilogue: C/D layout col=lane&15, row=quad*4+reg
#pragma unroll
    for (int i = 0; i < 4; ++i) {
        const size_t row0 = gm0 + wm * 64 + i * 16 + quad * 4;
#pragma unroll
        for (int j = 0; j < 4; ++j) {
            const size_t col = gn0 + wn * 64 + j * 16 + l16;
#pragma unroll
            for (int r = 0; r < 4; ++r)
                scores[(row0 + r) * NCPAD + col] = acc[i][j][r];
        }
    }
}

// ---- kernel 3: per-row argmax over first NC cols + one-hot write ----------
__global__ __launch_bounds__(256, 4)
void argmax_onehot_kernel(const float* __restrict__ scores, float* __restrict__ out)
{
    const int lane = threadIdx.x & 63;
    const int row  = blockIdx.x * 4 + (threadIdx.x >> 6);
    const float* srow = scores + (size_t)row * NCPAD;

    float bv = -INFINITY;
    int   bc = 0x7fffffff;
#pragma unroll
    for (int i = 0; i < 16; ++i) {
        const int c = lane + i * 64;
        if (c < NC) {
            const float v = srow[c];
            if (v > bv || (v == bv && c < bc)) { bv = v; bc = c; }
        }
    }
#pragma unroll
    for (int off = 32; off; off >>= 1) {
        const float ov = __shfl_down(bv, off);
        const int   oc = __shfl_down(bc, off);
        if (ov > bv || (ov == bv && oc < bc)) { bv = ov; bc = oc; }
    }
    bc = __shfl(bc, 0);

    float4* orow = (float4*)(out + (size_t)row * NC);   // 1000*4B: 16B-aligned
    for (int i = lane; i < NC / 4; i += 64) {
        const int cb = i * 4;
        float4 v;
        v.x = (cb     == bc) ? 1.f : 0.f;
        v.y = (cb + 1 == bc) ? 1.f : 0.f;
        v.z = (cb + 2 == bc) ? 1.f : 0.f;
        v.w = (cb + 3 == bc) ? 1.f : 0.f;
        orow[i] = v;
    }
}

// ===========================================================================
// Fallback: round-1 fp32 LDS-tiled kernel (correct, ~1.9 ms) if ws too small.
// ===========================================================================
#define MS 64
#define CS 256
#define KT 32
#define NCHUNK 4

__global__ __launch_bounds__(256, 1)
void nnc_fp32_kernel(const float* __restrict__ x,
                     const float* __restrict__ means,
                     float* __restrict__ out)
{
    __shared__ float xs[MS * KT];
    __shared__ float msh[CS * KT];
    __shared__ float rbest[MS * 33];
    __shared__ int   ridx[MS * 33];
    __shared__ int   widx[MS];

    const int tid = threadIdx.x;
    const int tx  = tid & 31;
    const int ty  = tid >> 5;
    const int s0  = blockIdx.x * MS;
    const int m0  = ty * 8;
    const int cL  = tx * 8;

    float best[8];
    int   bidx[8];
#pragma unroll
    for (int i = 0; i < 8; ++i) { best[i] = -INFINITY; bidx[i] = 0; }

    const int kslot = tid & 7;
    const int rrow  = tid >> 3;

    for (int chunk = 0; chunk < NCHUNK; ++chunk) {
        const int c0 = chunk * CS;
        float acc[8][8];
#pragma unroll
        for (int i = 0; i < 8; ++i)
#pragma unroll
            for (int j = 0; j < 8; ++j) acc[i][j] = 0.0f;

        for (int k0 = 0; k0 < ND; k0 += KT) {
#pragma unroll
            for (int r = 0; r < 2; ++r) {
                const int m = rrow + r * 32;
                const float4 v = *(const float4*)(x + (size_t)(s0 + m) * ND + k0 + kslot * 4);
                *(float4*)(xs + m * KT + kslot * 4) = v;
            }
#pragma unroll
            for (int r = 0; r < 8; ++r) {
                const int c  = rrow + r * 32;
                const int cg = c0 + c;
                float4 v = make_float4(0.f, 0.f, 0.f, 0.f);
                if (cg < NC) v = *(const float4*)(means + (size_t)cg * ND + k0 + kslot * 4);
                const int pslot = (kslot + (c >> 3)) & 7;
                *(float4*)(msh + c * KT + pslot * 4) = v;
            }
            __syncthreads();
#pragma unroll
            for (int k4 = 0; k4 < KT / 4; ++k4) {
                float4 a[8], b[8];
                const int boff = ((k4 + tx) & 7) * 4;
#pragma unroll
                for (int i = 0; i < 8; ++i) a[i] = *(const float4*)(xs + (m0 + i) * KT + k4 * 4);
#pragma unroll
                for (int j = 0; j < 8; ++j) b[j] = *(const float4*)(msh + (cL + j) * KT + boff);
#pragma unroll
                for (int i = 0; i < 8; ++i)
#pragma unroll
                    for (int j = 0; j < 8; ++j) {
                        acc[i][j] = fmaf(a[i].x, b[j].x, acc[i][j]);
                        acc[i][j] = fmaf(a[i].y, b[j].y, acc[i][j]);
                        acc[i][j] = fmaf(a[i].z, b[j].z, acc[i][j]);
                        acc[i][j] = fmaf(a[i].w, b[j].w, acc[i][j]);
                    }
            }
            __syncthreads();
        }
#pragma unroll
        for (int i = 0; i < 8; ++i)
#pragma unroll
            for (int j = 0; j < 8; ++j) {
                const int c = c0 + cL + j;
                const float v = acc[i][j];
                if (c < NC && (v > best[i] || (v == best[i] && c < bidx[i]))) {
                    best[i] = v; bidx[i] = c;
                }
            }
    }
#pragma unroll
    for (int i = 0; i < 8; ++i) {
        rbest[(m0 + i) * 33 + tx] = best[i];
        ridx[(m0 + i) * 33 + tx]  = bidx[i];
    }
    __syncthreads();
    if (tid < MS) {
        float bv = rbest[tid * 33];
        int   bc = ridx[tid * 33];
        for (int t = 1; t < 32; ++t) {
            const float v = rbest[tid * 33 + t];
            const int   c = ridx[tid * 33 + t];
            if (v > bv || (v == bv && c < bc)) { bv = v; bc = c; }
        }
        widx[tid] = bc;
    }
    __syncthreads();
    if (tid < 250) {
        const int cbase = tid * 4;
        for (int m = 0; m < MS; ++m) {
            const int w = widx[m];
            float4 v;
            v.x = (cbase == w) ? 1.f : 0.f;
            v.y = (cbase + 1 == w) ? 1.f : 0.f;
            v.z = (cbase + 2 == w) ? 1.f : 0.f;
            v.w = (cbase + 3 == w) ? 1.f : 0.f;
            *(float4*)(out + (size_t)(s0 + m) * NC + cbase) = v;
        }
    }
}

extern "C" void kernel_launch(void* const* d_in, const int* in_sizes, int n_in,
                              void* d_out, int out_size, void* d_ws, size_t ws_size,
                              hipStream_t stream) {
    const float* x     = (const float*)d_in[0];
    const float* means = (const float*)d_in[1];
    float* out         = (float*)d_out;

    if (ws_size >= WS_NEEDED) {
        char* ws = (char*)d_ws;
        _Float16* xhi = (_Float16*)ws;
        _Float16* xlo = xhi + (size_t)NS * ND;
        _Float16* mhi = (_Float16*)(ws + 134217728ull);
        _Float16* mlo = mhi + (size_t)NCPAD * ND;
        float* scores = (float*)(ws + 134217728ull + 8388608ull);

        split_x_kernel<<<dim3(NS * ND / 4 / 256), dim3(256), 0, stream>>>(x, xhi, xlo);
        split_m_kernel<<<dim3(NCPAD * ND / 4 / 256), dim3(256), 0, stream>>>(means, mhi, mlo);
        gemm_split_kernel<<<dim3(NS / 128, NCPAD / 128), dim3(256), 0, stream>>>(
            xhi, xlo, mhi, mlo, scores);
        argmax_onehot_kernel<<<dim3(NS / 4), dim3(256), 0, stream>>>(scores, out);
    } else {
        nnc_fp32_kernel<<<dim3(NS / MS), dim3(256), 0, stream>>>(x, means, out);
    }
}

// Round 4
// 406.492 us; speedup vs baseline: 4.6976x; 1.1161x over previous
//
#include <hip/hip_runtime.h>
#include <math.h>

// Problem shape (fixed by the bench's setup_inputs)
#define NS 16384
#define ND 2048
#define NC 1000
#define NCPAD 1024

typedef _Float16 f16x8 __attribute__((ext_vector_type(8)));
typedef _Float16 f16x4 __attribute__((ext_vector_type(4)));
typedef __fp16   h16x2 __attribute__((ext_vector_type(2)));   // cvt_pkrtz result type
typedef float f32x4 __attribute__((ext_vector_type(4)));

// Workspace: mhi (4 MB) + mlo (4 MB) + cand (16384*8*8 B = 1 MB) = 9 MB
#define WS_NEEDED 9437184ull

__device__ __forceinline__ void gl_lds16_h(const _Float16* g, _Float16* l) {
    __builtin_amdgcn_global_load_lds(
        (const __attribute__((address_space(1))) unsigned int*)g,
        (__attribute__((address_space(3))) unsigned int*)l, 16, 0, 0);
}
__device__ __forceinline__ void gl_lds16_f(const float* g, float* l) {
    __builtin_amdgcn_global_load_lds(
        (const __attribute__((address_space(1))) unsigned int*)g,
        (__attribute__((address_space(3))) unsigned int*)l, 16, 0, 0);
}

// fp32x8 -> f16 hi/lo split (hi via RTZ pack; lo = RN(x - hi), |err| ~ 2^-21|x|)
__device__ __forceinline__ void split8(const f32x4 a0, const f32x4 a1,
                                       f16x8& h, f16x8& l) {
    const h16x2 h01 = __builtin_amdgcn_cvt_pkrtz(a0[0], a0[1]);
    const h16x2 h23 = __builtin_amdgcn_cvt_pkrtz(a0[2], a0[3]);
    const h16x2 h45 = __builtin_amdgcn_cvt_pkrtz(a1[0], a1[1]);
    const h16x2 h67 = __builtin_amdgcn_cvt_pkrtz(a1[2], a1[3]);
    const h16x2 l01 = __builtin_amdgcn_cvt_pkrtz(a0[0] - (float)h01[0], a0[1] - (float)h01[1]);
    const h16x2 l23 = __builtin_amdgcn_cvt_pkrtz(a0[2] - (float)h23[0], a0[3] - (float)h23[1]);
    const h16x2 l45 = __builtin_amdgcn_cvt_pkrtz(a1[0] - (float)h45[0], a1[1] - (float)h45[1]);
    const h16x2 l67 = __builtin_amdgcn_cvt_pkrtz(a1[2] - (float)h67[0], a1[3] - (float)h67[1]);
    h[0]=(_Float16)h01[0]; h[1]=(_Float16)h01[1]; h[2]=(_Float16)h23[0]; h[3]=(_Float16)h23[1];
    h[4]=(_Float16)h45[0]; h[5]=(_Float16)h45[1]; h[6]=(_Float16)h67[0]; h[7]=(_Float16)h67[1];
    l[0]=(_Float16)l01[0]; l[1]=(_Float16)l01[1]; l[2]=(_Float16)l23[0]; l[3]=(_Float16)l23[1];
    l[4]=(_Float16)l45[0]; l[5]=(_Float16)l45[1]; l[6]=(_Float16)l67[0]; l[7]=(_Float16)l67[1];
}

// ---- kernel 1: split means (fp32 -> f16 hi/lo), zero-padded to NCPAD rows --
__global__ __launch_bounds__(256)
void split_m_kernel(const float* __restrict__ src,
                    _Float16* __restrict__ hi, _Float16* __restrict__ lo)
{
    const int i = blockIdx.x * 256 + threadIdx.x;   // float4 slot, < NCPAD*ND/4
    const int row = (i * 4) >> 11;                  // /ND
    float4 v = make_float4(0.f, 0.f, 0.f, 0.f);
    if (row < NC) v = ((const float4*)src)[i];
    f16x4 h, l;
    h[0] = (_Float16)v.x; l[0] = (_Float16)(v.x - (float)h[0]);
    h[1] = (_Float16)v.y; l[1] = (_Float16)(v.y - (float)h[1]);
    h[2] = (_Float16)v.z; l[2] = (_Float16)(v.z - (float)h[2]);
    h[3] = (_Float16)v.w; l[3] = (_Float16)(v.w - (float)h[3]);
    ((f16x4*)hi)[i] = h;
    ((f16x4*)lo)[i] = l;
}

// ---- kernel 2: fused split-f16 MFMA GEMM + per-block column argmax ---------
// grid (NS/128 rowblocks, NCPAD/128 colblocks); 256 threads = 2x2 waves;
// wave tile 64x64 = 4x4 MFMAs of 16x16x32 f16, 3 passes (hh + hl + lh).
// A staged as raw fp32 (same bytes as hi+lo f16), split in-register.
// LDS chunk swizzle on the GLOBAL source address (global_load_lds pins the
// LDS dest to lane order): A chunk^=(row&7), B chunk^=((row>>1)&3) ->
// fragment ds_read_b128s become 2-way (free) instead of 8/16-way conflicts.
// Epilogue: per-row argmax over this block's 128 cols -> cand[row][colblock].
__global__ __launch_bounds__(256, 2)
void gemm_fused_kernel(const float* __restrict__ x,
                       const _Float16* __restrict__ mhi,
                       const _Float16* __restrict__ mlo,
                       float2* __restrict__ cand)
{
    __shared__ float    sA [128 * 32];   // 16 KB fp32 x tile
    __shared__ _Float16 sBh[128 * 32];   // 8 KB
    __shared__ _Float16 sBl[128 * 32];   // 8 KB
    __shared__ float    rv[128 * 2];     // epilogue [row][wn]
    __shared__ int      rc[128 * 2];

    const int tid  = threadIdx.x;
    const int lane = tid & 63;
    const int w    = tid >> 6;
    const int wm   = w & 1, wn = w >> 1;
    const int quad = lane >> 4, l16 = lane & 15;
    const size_t gm0 = (size_t)blockIdx.x * 128;
    const size_t gn0 = (size_t)blockIdx.y * 128;

    f32x4 acc[4][4] = {};

    for (int kt = 0; kt < ND / 32; ++kt) {
        const int k0 = kt * 32;
        // A: 128 rows x 32 fp32 (8 chunks of 16B per row), 1024 slots / 256 thr
#pragma unroll
        for (int r = 0; r < 4; ++r) {
            const int slot = r * 256 + tid;
            const int row  = slot >> 3;
            const int kcg  = (slot & 7) ^ (row & 7);
            const size_t ga = ((gm0 + row) << 11) + k0 + kcg * 4;
            gl_lds16_f(x + ga, &sA[(r * 256 + w * 64) * 4]);
        }
        // B: 2 arrays, 128 rows x 32 halves (4 chunks of 16B per row)
#pragma unroll
        for (int r = 0; r < 2; ++r) {
            const int slot = r * 256 + tid;
            const int row  = slot >> 2;
            const int kcg  = (slot & 3) ^ ((row >> 1) & 3);
            const size_t gb = ((gn0 + row) << 11) + k0 + kcg * 8;
            const int lbase = (r * 256 + w * 64) * 8;
            gl_lds16_h(mhi + gb, &sBh[lbase]);
            gl_lds16_h(mlo + gb, &sBl[lbase]);
        }
        __syncthreads();

        f16x8 ah[4], al[4], bh[4], bl[4];
#pragma unroll
        for (int i = 0; i < 4; ++i) {
            const int br = wn * 64 + i * 16 + l16;
            const int pb = quad ^ ((br >> 1) & 3);          // physical B chunk
            bh[i] = *(const f16x8*)&sBh[br * 32 + pb * 8];
            bl[i] = *(const f16x8*)&sBl[br * 32 + pb * 8];
            const int ar = wm * 64 + i * 16 + l16;
            const int c1 = (2 * quad)     ^ (ar & 7);       // physical A chunks
            const int c2 = (2 * quad + 1) ^ (ar & 7);
            const f32x4 a0 = *(const f32x4*)&sA[ar * 32 + c1 * 4];
            const f32x4 a1 = *(const f32x4*)&sA[ar * 32 + c2 * 4];
            split8(a0, a1, ah[i], al[i]);
        }
#pragma unroll
        for (int i = 0; i < 4; ++i)
#pragma unroll
            for (int j = 0; j < 4; ++j) {
                acc[i][j] = __builtin_amdgcn_mfma_f32_16x16x32_f16(ah[i], bh[j], acc[i][j], 0, 0, 0);
                acc[i][j] = __builtin_amdgcn_mfma_f32_16x16x32_f16(ah[i], bl[j], acc[i][j], 0, 0, 0);
                acc[i][j] = __builtin_amdgcn_mfma_f32_16x16x32_f16(al[i], bh[j], acc[i][j], 0, 0, 0);
            }
        __syncthreads();
    }

    // ---- epilogue: per-row argmax over this block's 128 columns ----
    // C/D layout: col = l16 + j*16 + wn*64, row = wm*64 + i*16 + quad*4 + r
#pragma unroll
    for (int i = 0; i < 4; ++i)
#pragma unroll
        for (int r = 0; r < 4; ++r) {
            float bv = -INFINITY;
            int   bc = 0x7fffffff;
#pragma unroll
            for (int j = 0; j < 4; ++j) {
                const int col = (int)gn0 + wn * 64 + j * 16 + l16;
                const float v = acc[i][j][r];
                if (col < NC && (v > bv || (v == bv && col < bc))) { bv = v; bc = col; }
            }
#pragma unroll
            for (int off = 1; off < 16; off <<= 1) {   // reduce across l16
                const float ov = __shfl_xor(bv, off);
                const int   oc = __shfl_xor(bc, off);
                if (ov > bv || (ov == bv && oc < bc)) { bv = ov; bc = oc; }
            }
            if (l16 == 0) {
                const int lrow = wm * 64 + i * 16 + quad * 4 + r;
                rv[lrow * 2 + wn] = bv;
                rc[lrow * 2 + wn] = bc;
            }
        }
    __syncthreads();
    if (tid < 128) {
        float bv = rv[tid * 2];
        int   bc = rc[tid * 2];
        const float ov = rv[tid * 2 + 1];
        const int   oc = rc[tid * 2 + 1];
        if (ov > bv || (ov == bv && oc < bc)) { bv = ov; bc = oc; }
        cand[(gm0 + tid) * 8 + blockIdx.y] = make_float2(bv, __int_as_float(bc));
    }
}

// ---- kernel 3: reduce 8 candidates per row, write one-hot ------------------
__global__ __launch_bounds__(256, 4)
void finalize_kernel(const float2* __restrict__ cand, float* __restrict__ out)
{
    const int lane = threadIdx.x & 63;
    const int row  = blockIdx.x * 4 + (threadIdx.x >> 6);

    float bv = -INFINITY;
    int   bc = 0x7fffffff;
    if (lane < 8) {
        const float2 c = cand[(size_t)row * 8 + lane];
        bv = c.x;
        bc = __float_as_int(c.y);
    }
#pragma unroll
    for (int off = 1; off < 8; off <<= 1) {
        const float ov = __shfl_xor(bv, off);
        const int   oc = __shfl_xor(bc, off);
        if (ov > bv || (ov == bv && oc < bc)) { bv = ov; bc = oc; }
    }
    bc = __shfl(bc, 0);

    float4* orow = (float4*)(out + (size_t)row * NC);
#pragma unroll
    for (int i = 0; i < 4; ++i) {
        const int idx = lane + i * 64;
        if (idx < NC / 4) {
            const int cb = idx * 4;
            float4 v;
            v.x = (cb     == bc) ? 1.f : 0.f;
            v.y = (cb + 1 == bc) ? 1.f : 0.f;
            v.z = (cb + 2 == bc) ? 1.f : 0.f;
            v.w = (cb + 3 == bc) ? 1.f : 0.f;
            orow[idx] = v;
        }
    }
}

// ===========================================================================
// Fallback: round-1 fp32 LDS-tiled kernel (correct, ~1.9 ms) if ws too small.
// ===========================================================================
#define MS 64
#define CS 256
#define KT 32
#define NCHUNK 4

__global__ __launch_bounds__(256, 1)
void nnc_fp32_kernel(const float* __restrict__ x,
                     const float* __restrict__ means,
                     float* __restrict__ out)
{
    __shared__ float xs[MS * KT];
    __shared__ float msh[CS * KT];
    __shared__ float rbest[MS * 33];
    __shared__ int   ridx[MS * 33];
    __shared__ int   widx[MS];

    const int tid = threadIdx.x;
    const int tx  = tid & 31;
    const int ty  = tid >> 5;
    const int s0  = blockIdx.x * MS;
    const int m0  = ty * 8;
    const int cL  = tx * 8;

    float best[8];
    int   bidx[8];
#pragma unroll
    for (int i = 0; i < 8; ++i) { best[i] = -INFINITY; bidx[i] = 0; }

    const int kslot = tid & 7;
    const int rrow  = tid >> 3;

    for (int chunk = 0; chunk < NCHUNK; ++chunk) {
        const int c0 = chunk * CS;
        float acc[8][8];
#pragma unroll
        for (int i = 0; i < 8; ++i)
#pragma unroll
            for (int j = 0; j < 8; ++j) acc[i][j] = 0.0f;

        for (int k0 = 0; k0 < ND; k0 += KT) {
#pragma unroll
            for (int r = 0; r < 2; ++r) {
                const int m = rrow + r * 32;
                const float4 v = *(const float4*)(x + (size_t)(s0 + m) * ND + k0 + kslot * 4);
                *(float4*)(xs + m * KT + kslot * 4) = v;
            }
#pragma unroll
            for (int r = 0; r < 8; ++r) {
                const int c  = rrow + r * 32;
                const int cg = c0 + c;
                float4 v = make_float4(0.f, 0.f, 0.f, 0.f);
                if (cg < NC) v = *(const float4*)(means + (size_t)cg * ND + k0 + kslot * 4);
                const int pslot = (kslot + (c >> 3)) & 7;
                *(float4*)(msh + c * KT + pslot * 4) = v;
            }
            __syncthreads();
#pragma unroll
            for (int k4 = 0; k4 < KT / 4; ++k4) {
                float4 a[8], b[8];
                const int boff = ((k4 + tx) & 7) * 4;
#pragma unroll
                for (int i = 0; i < 8; ++i) a[i] = *(const float4*)(xs + (m0 + i) * KT + k4 * 4);
#pragma unroll
                for (int j = 0; j < 8; ++j) b[j] = *(const float4*)(msh + (cL + j) * KT + boff);
#pragma unroll
                for (int i = 0; i < 8; ++i)
#pragma unroll
                    for (int j = 0; j < 8; ++j) {
                        acc[i][j] = fmaf(a[i].x, b[j].x, acc[i][j]);
                        acc[i][j] = fmaf(a[i].y, b[j].y, acc[i][j]);
                        acc[i][j] = fmaf(a[i].z, b[j].z, acc[i][j]);
                        acc[i][j] = fmaf(a[i].w, b[j].w, acc[i][j]);
                    }
            }
            __syncthreads();
        }
#pragma unroll
        for (int i = 0; i < 8; ++i)
#pragma unroll
            for (int j = 0; j < 8; ++j) {
                const int c = c0 + cL + j;
                const float v = acc[i][j];
                if (c < NC && (v > best[i] || (v == best[i] && c < bidx[i]))) {
                    best[i] = v; bidx[i] = c;
                }
            }
    }
#pragma unroll
    for (int i = 0; i < 8; ++i) {
        rbest[(m0 + i) * 33 + tx] = best[i];
        ridx[(m0 + i) * 33 + tx]  = bidx[i];
    }
    __syncthreads();
    if (tid < MS) {
        float bv = rbest[tid * 33];
        int   bc = ridx[tid * 33];
        for (int t = 1; t < 32; ++t) {
            const float v = rbest[tid * 33 + t];
            const int   c = ridx[tid * 33 + t];
            if (v > bv || (v == bv && c < bc)) { bv = v; bc = c; }
        }
        widx[tid] = bc;
    }
    __syncthreads();
    if (tid < 250) {
        const int cbase = tid * 4;
        for (int m = 0; m < MS; ++m) {
            const int w = widx[m];
            float4 v;
            v.x = (cbase == w) ? 1.f : 0.f;
            v.y = (cbase + 1 == w) ? 1.f : 0.f;
            v.z = (cbase + 2 == w) ? 1.f : 0.f;
            v.w = (cbase + 3 == w) ? 1.f : 0.f;
            *(float4*)(out + (size_t)(s0 + m) * NC + cbase) = v;
        }
    }
}

extern "C" void kernel_launch(void* const* d_in, const int* in_sizes, int n_in,
                              void* d_out, int out_size, void* d_ws, size_t ws_size,
                              hipStream_t stream) {
    const float* x     = (const float*)d_in[0];
    const float* means = (const float*)d_in[1];
    float* out         = (float*)d_out;

    if (ws_size >= WS_NEEDED) {
        char* ws = (char*)d_ws;
        _Float16* mhi = (_Float16*)ws;
        _Float16* mlo = mhi + (size_t)NCPAD * ND;
        float2*  cand = (float2*)(ws + 8388608ull);

        split_m_kernel<<<dim3(NCPAD * ND / 4 / 256), dim3(256), 0, stream>>>(means, mhi, mlo);
        gemm_fused_kernel<<<dim3(NS / 128, NCPAD / 128), dim3(256), 0, stream>>>(
            x, mhi, mlo, cand);
        finalize_kernel<<<dim3(NS / 4), dim3(256), 0, stream>>>(cand, out);
    } else {
        nnc_fp32_kernel<<<dim3(NS / MS), dim3(256), 0, stream>>>(x, means, out);
    }
}

// Round 5
// 363.279 us; speedup vs baseline: 5.2564x; 1.1190x over previous
//
#include <hip/hip_runtime.h>
#include <math.h>

// Problem shape (fixed by the bench's setup_inputs)
#define NS 16384
#define ND 2048
#define NC 1000
#define NCPAD 1024

typedef _Float16 f16x8 __attribute__((ext_vector_type(8)));
typedef _Float16 f16x4 __attribute__((ext_vector_type(4)));
typedef __fp16   h16x2 __attribute__((ext_vector_type(2)));   // cvt_pkrtz result type
typedef float f32x4 __attribute__((ext_vector_type(4)));

// Workspace: mhi (4 MB) + mlo (4 MB) + cand (16384*4*8 B = 512 KB) = 8.5 MB
#define WS_NEEDED 9437184ull

__device__ __forceinline__ void gl_lds16_h(const _Float16* g, _Float16* l) {
    __builtin_amdgcn_global_load_lds(
        (const __attribute__((address_space(1))) unsigned int*)g,
        (__attribute__((address_space(3))) unsigned int*)l, 16, 0, 0);
}
__device__ __forceinline__ void gl_lds16_f(const float* g, float* l) {
    __builtin_amdgcn_global_load_lds(
        (const __attribute__((address_space(1))) unsigned int*)g,
        (__attribute__((address_space(3))) unsigned int*)l, 16, 0, 0);
}

// fp32x8 -> f16 hi/lo split (hi via RTZ pack; lo = RN(x - hi), |err| ~ 2^-21|x|)
__device__ __forceinline__ void split8(const f32x4 a0, const f32x4 a1,
                                       f16x8& h, f16x8& l) {
    const h16x2 h01 = __builtin_amdgcn_cvt_pkrtz(a0[0], a0[1]);
    const h16x2 h23 = __builtin_amdgcn_cvt_pkrtz(a0[2], a0[3]);
    const h16x2 h45 = __builtin_amdgcn_cvt_pkrtz(a1[0], a1[1]);
    const h16x2 h67 = __builtin_amdgcn_cvt_pkrtz(a1[2], a1[3]);
    const h16x2 l01 = __builtin_amdgcn_cvt_pkrtz(a0[0] - (float)h01[0], a0[1] - (float)h01[1]);
    const h16x2 l23 = __builtin_amdgcn_cvt_pkrtz(a0[2] - (float)h23[0], a0[3] - (float)h23[1]);
    const h16x2 l45 = __builtin_amdgcn_cvt_pkrtz(a1[0] - (float)h45[0], a1[1] - (float)h45[1]);
    const h16x2 l67 = __builtin_amdgcn_cvt_pkrtz(a1[2] - (float)h67[0], a1[3] - (float)h67[1]);
    h[0]=(_Float16)h01[0]; h[1]=(_Float16)h01[1]; h[2]=(_Float16)h23[0]; h[3]=(_Float16)h23[1];
    h[4]=(_Float16)h45[0]; h[5]=(_Float16)h45[1]; h[6]=(_Float16)h67[0]; h[7]=(_Float16)h67[1];
    l[0]=(_Float16)l01[0]; l[1]=(_Float16)l01[1]; l[2]=(_Float16)l23[0]; l[3]=(_Float16)l23[1];
    l[4]=(_Float16)l45[0]; l[5]=(_Float16)l45[1]; l[6]=(_Float16)l67[0]; l[7]=(_Float16)l67[1];
}

// ---- kernel 1: split means (fp32 -> f16 hi/lo), zero-padded to NCPAD rows --
__global__ __launch_bounds__(256)
void split_m_kernel(const float* __restrict__ src,
                    _Float16* __restrict__ hi, _Float16* __restrict__ lo)
{
    const int i = blockIdx.x * 256 + threadIdx.x;   // float4 slot, < NCPAD*ND/4
    const int row = (i * 4) >> 11;                  // /ND
    float4 v = make_float4(0.f, 0.f, 0.f, 0.f);
    if (row < NC) v = ((const float4*)src)[i];
    f16x4 h, l;
    h[0] = (_Float16)v.x; l[0] = (_Float16)(v.x - (float)h[0]);
    h[1] = (_Float16)v.y; l[1] = (_Float16)(v.y - (float)h[1]);
    h[2] = (_Float16)v.z; l[2] = (_Float16)(v.z - (float)h[2]);
    h[3] = (_Float16)v.w; l[3] = (_Float16)(v.w - (float)h[3]);
    ((f16x4*)hi)[i] = h;
    ((f16x4*)lo)[i] = l;
}

// ---- kernel 2: fused split-f16 MFMA GEMM + per-block column argmax ---------
// Block tile 128 rows x 256 cols; grid (NCPAD/256=4 colblocks fast, NS/128=128).
// 256 threads = 2x2 waves; wave tile 64x128 = 4x8 MFMAs of 16x16x32 f16,
// 3 passes (hh + hl + lh) -> 96 MFMA (~466 cyc) vs ~96 split-VALU (~330 cyc)
// per k-tile per wave: MFMA is the binding pipe (was 48:96 = VALU-bound).
// A staged as raw fp32, split in-register. Chunk swizzles keep ds_read_b128
// at the 8-lane/bank-group optimum: A chunk^=(row&7), B chunk^=(row&3).
__global__ __launch_bounds__(256, 2)
void gemm_fused_kernel(const float* __restrict__ x,
                       const _Float16* __restrict__ mhi,
                       const _Float16* __restrict__ mlo,
                       float2* __restrict__ cand)
{
    __shared__ float    sA [128 * 32];   // 16 KB fp32 x tile
    __shared__ _Float16 sBh[256 * 32];   // 16 KB
    __shared__ _Float16 sBl[256 * 32];   // 16 KB
    __shared__ float    rv[128 * 2];     // epilogue [row][wn]
    __shared__ int      rc[128 * 2];

    const int tid  = threadIdx.x;
    const int lane = tid & 63;
    const int w    = tid >> 6;
    const int wm   = w & 1, wn = w >> 1;
    const int quad = lane >> 4, l16 = lane & 15;
    const size_t gm0 = (size_t)blockIdx.y * 128;   // sample rows
    const size_t gn0 = (size_t)blockIdx.x * 256;   // class cols

    f32x4 acc[4][8] = {};

    for (int kt = 0; kt < ND / 32; ++kt) {
        const int k0 = kt * 32;
        // A: 128 rows x 32 fp32 = 1024 16B-chunks / 256 thr
#pragma unroll
        for (int r = 0; r < 4; ++r) {
            const int slot = r * 256 + tid;
            const int row  = slot >> 3;
            const int kcg  = (slot & 7) ^ (row & 7);
            const size_t ga = ((gm0 + row) << 11) + k0 + kcg * 4;
            gl_lds16_f(x + ga, &sA[(r * 256 + w * 64) * 4]);
        }
        // B: 2 arrays, 256 rows x 32 halves = 1024 16B-chunks each
#pragma unroll
        for (int r = 0; r < 4; ++r) {
            const int slot = r * 256 + tid;
            const int row  = slot >> 2;
            const int kcg  = (slot & 3) ^ (row & 3);
            const size_t gb = ((gn0 + row) << 11) + k0 + kcg * 8;
            const int lbase = (r * 256 + w * 64) * 8;
            gl_lds16_h(mhi + gb, &sBh[lbase]);
            gl_lds16_h(mlo + gb, &sBl[lbase]);
        }
        __syncthreads();

        f16x8 ah[4], al[4];
#pragma unroll
        for (int t = 0; t < 4; ++t) {
            const int ar = wm * 64 + t * 16 + l16;
            const int c1 = (2 * quad)     ^ (ar & 7);
            const int c2 = (2 * quad + 1) ^ (ar & 7);
            const f32x4 a0 = *(const f32x4*)&sA[ar * 32 + c1 * 4];
            const f32x4 a1 = *(const f32x4*)&sA[ar * 32 + c2 * 4];
            split8(a0, a1, ah[t], al[t]);
        }
#pragma unroll
        for (int j = 0; j < 8; ++j) {
            const int br = wn * 128 + j * 16 + l16;
            const int pb = quad ^ (br & 3);
            const f16x8 bh = *(const f16x8*)&sBh[br * 32 + pb * 8];
            const f16x8 bl = *(const f16x8*)&sBl[br * 32 + pb * 8];
#pragma unroll
            for (int t = 0; t < 4; ++t) {
                acc[t][j] = __builtin_amdgcn_mfma_f32_16x16x32_f16(ah[t], bh, acc[t][j], 0, 0, 0);
                acc[t][j] = __builtin_amdgcn_mfma_f32_16x16x32_f16(ah[t], bl, acc[t][j], 0, 0, 0);
                acc[t][j] = __builtin_amdgcn_mfma_f32_16x16x32_f16(al[t], bh, acc[t][j], 0, 0, 0);
            }
        }
        __syncthreads();
    }

    // ---- epilogue: per-row argmax over this block's 256 columns ----
    // C/D layout: col = gn0 + wn*128 + j*16 + l16, row = wm*64 + t*16 + quad*4 + r
#pragma unroll
    for (int t = 0; t < 4; ++t)
#pragma unroll
        for (int r = 0; r < 4; ++r) {
            float bv = -INFINITY;
            int   bc = 0x7fffffff;
#pragma unroll
            for (int j = 0; j < 8; ++j) {
                const int col = (int)gn0 + wn * 128 + j * 16 + l16;
                const float v = acc[t][j][r];
                if (col < NC && (v > bv || (v == bv && col < bc))) { bv = v; bc = col; }
            }
#pragma unroll
            for (int off = 1; off < 16; off <<= 1) {   // reduce across l16
                const float ov = __shfl_xor(bv, off);
                const int   oc = __shfl_xor(bc, off);
                if (ov > bv || (ov == bv && oc < bc)) { bv = ov; bc = oc; }
            }
            if (l16 == 0) {
                const int lrow = wm * 64 + t * 16 + quad * 4 + r;
                rv[lrow * 2 + wn] = bv;
                rc[lrow * 2 + wn] = bc;
            }
        }
    __syncthreads();
    if (tid < 128) {
        float bv = rv[tid * 2];
        int   bc = rc[tid * 2];
        const float ov = rv[tid * 2 + 1];
        const int   oc = rc[tid * 2 + 1];
        if (ov > bv || (ov == bv && oc < bc)) { bv = ov; bc = oc; }
        cand[(gm0 + tid) * 4 + blockIdx.x] = make_float2(bv, __int_as_float(bc));
    }
}

// ---- kernel 3: reduce 4 candidates per row, write one-hot ------------------
__global__ __launch_bounds__(256, 4)
void finalize_kernel(const float2* __restrict__ cand, float* __restrict__ out)
{
    const int lane = threadIdx.x & 63;
    const int row  = blockIdx.x * 4 + (threadIdx.x >> 6);

    float bv = -INFINITY;
    int   bc = 0x7fffffff;
    if (lane < 4) {
        const float2 c = cand[(size_t)row * 4 + lane];
        bv = c.x;
        bc = __float_as_int(c.y);
    }
#pragma unroll
    for (int off = 1; off < 4; off <<= 1) {
        const float ov = __shfl_xor(bv, off);
        const int   oc = __shfl_xor(bc, off);
        if (ov > bv || (ov == bv && oc < bc)) { bv = ov; bc = oc; }
    }
    bc = __shfl(bc, 0);

    float4* orow = (float4*)(out + (size_t)row * NC);
#pragma unroll
    for (int i = 0; i < 4; ++i) {
        const int idx = lane + i * 64;
        if (idx < NC / 4) {
            const int cb = idx * 4;
            float4 v;
            v.x = (cb     == bc) ? 1.f : 0.f;
            v.y = (cb + 1 == bc) ? 1.f : 0.f;
            v.z = (cb + 2 == bc) ? 1.f : 0.f;
            v.w = (cb + 3 == bc) ? 1.f : 0.f;
            orow[idx] = v;
        }
    }
}

// ===========================================================================
// Fallback: round-1 fp32 LDS-tiled kernel (correct, ~1.9 ms) if ws too small.
// ===========================================================================
#define MS 64
#define CS 256
#define KT 32
#define NCHUNK 4

__global__ __launch_bounds__(256, 1)
void nnc_fp32_kernel(const float* __restrict__ x,
                     const float* __restrict__ means,
                     float* __restrict__ out)
{
    __shared__ float xs[MS * KT];
    __shared__ float msh[CS * KT];
    __shared__ float rbest[MS * 33];
    __shared__ int   ridx[MS * 33];
    __shared__ int   widx[MS];

    const int tid = threadIdx.x;
    const int tx  = tid & 31;
    const int ty  = tid >> 5;
    const int s0  = blockIdx.x * MS;
    const int m0  = ty * 8;
    const int cL  = tx * 8;

    float best[8];
    int   bidx[8];
#pragma unroll
    for (int i = 0; i < 8; ++i) { best[i] = -INFINITY; bidx[i] = 0; }

    const int kslot = tid & 7;
    const int rrow  = tid >> 3;

    for (int chunk = 0; chunk < NCHUNK; ++chunk) {
        const int c0 = chunk * CS;
        float acc[8][8];
#pragma unroll
        for (int i = 0; i < 8; ++i)
#pragma unroll
            for (int j = 0; j < 8; ++j) acc[i][j] = 0.0f;

        for (int k0 = 0; k0 < ND; k0 += KT) {
#pragma unroll
            for (int r = 0; r < 2; ++r) {
                const int m = rrow + r * 32;
                const float4 v = *(const float4*)(x + (size_t)(s0 + m) * ND + k0 + kslot * 4);
                *(float4*)(xs + m * KT + kslot * 4) = v;
            }
#pragma unroll
            for (int r = 0; r < 8; ++r) {
                const int c  = rrow + r * 32;
                const int cg = c0 + c;
                float4 v = make_float4(0.f, 0.f, 0.f, 0.f);
                if (cg < NC) v = *(const float4*)(means + (size_t)cg * ND + k0 + kslot * 4);
                const int pslot = (kslot + (c >> 3)) & 7;
                *(float4*)(msh + c * KT + pslot * 4) = v;
            }
            __syncthreads();
#pragma unroll
            for (int k4 = 0; k4 < KT / 4; ++k4) {
                float4 a[8], b[8];
                const int boff = ((k4 + tx) & 7) * 4;
#pragma unroll
                for (int i = 0; i < 8; ++i) a[i] = *(const float4*)(xs + (m0 + i) * KT + k4 * 4);
#pragma unroll
                for (int j = 0; j < 8; ++j) b[j] = *(const float4*)(msh + (cL + j) * KT + boff);
#pragma unroll
                for (int i = 0; i < 8; ++i)
#pragma unroll
                    for (int j = 0; j < 8; ++j) {
                        acc[i][j] = fmaf(a[i].x, b[j].x, acc[i][j]);
                        acc[i][j] = fmaf(a[i].y, b[j].y, acc[i][j]);
                        acc[i][j] = fmaf(a[i].z, b[j].z, acc[i][j]);
                        acc[i][j] = fmaf(a[i].w, b[j].w, acc[i][j]);
                    }
            }
            __syncthreads();
        }
#pragma unroll
        for (int i = 0; i < 8; ++i)
#pragma unroll
            for (int j = 0; j < 8; ++j) {
                const int c = c0 + cL + j;
                const float v = acc[i][j];
                if (c < NC && (v > best[i] || (v == best[i] && c < bidx[i]))) {
                    best[i] = v; bidx[i] = c;
                }
            }
    }
#pragma unroll
    for (int i = 0; i < 8; ++i) {
        rbest[(m0 + i) * 33 + tx] = best[i];
        ridx[(m0 + i) * 33 + tx]  = bidx[i];
    }
    __syncthreads();
    if (tid < MS) {
        float bv = rbest[tid * 33];
        int   bc = ridx[tid * 33];
        for (int t = 1; t < 32; ++t) {
            const float v = rbest[tid * 33 + t];
            const int   c = ridx[tid * 33 + t];
            if (v > bv || (v == bv && c < bc)) { bv = v; bc = c; }
        }
        widx[tid] = bc;
    }
    __syncthreads();
    if (tid < 250) {
        const int cbase = tid * 4;
        for (int m = 0; m < MS; ++m) {
            const int w = widx[m];
            float4 v;
            v.x = (cbase == w) ? 1.f : 0.f;
            v.y = (cbase + 1 == w) ? 1.f : 0.f;
            v.z = (cbase + 2 == w) ? 1.f : 0.f;
            v.w = (cbase + 3 == w) ? 1.f : 0.f;
            *(float4*)(out + (size_t)(s0 + m) * NC + cbase) = v;
        }
    }
}

extern "C" void kernel_launch(void* const* d_in, const int* in_sizes, int n_in,
                              void* d_out, int out_size, void* d_ws, size_t ws_size,
                              hipStream_t stream) {
    const float* x     = (const float*)d_in[0];
    const float* means = (const float*)d_in[1];
    float* out         = (float*)d_out;

    if (ws_size >= WS_NEEDED) {
        char* ws = (char*)d_ws;
        _Float16* mhi = (_Float16*)ws;
        _Float16* mlo = mhi + (size_t)NCPAD * ND;
        float2*  cand = (float2*)(ws + 8388608ull);

        split_m_kernel<<<dim3(NCPAD * ND / 4 / 256), dim3(256), 0, stream>>>(means, mhi, mlo);
        gemm_fused_kernel<<<dim3(NCPAD / 256, NS / 128), dim3(256), 0, stream>>>(
            x, mhi, mlo, cand);
        finalize_kernel<<<dim3(NS / 4), dim3(256), 0, stream>>>(cand, out);
    } else {
        nnc_fp32_kernel<<<dim3(NS / MS), dim3(256), 0, stream>>>(x, means, out);
    }
}